// Round 4
// baseline (229.953 us; speedup 1.0000x reference)
//
#include <hip/hip_runtime.h>
#include <math.h>

#define DIM    64
#define N_MEM  32
#define N_ITEM 10000
#define HOPS   2
#define BATCH  4096
#define HIST   50

typedef float4 f4;

// Layout: lane = g*16 + p. g = memory subgroup (4 rows gathered per instr),
// p = float4 slot within a 64-float row. One wave instr = 4 rows x 256B.
// One wave per (item, hop): hops are independent in the reference
// (acc = item_emb + sum_h softmax_h . tails_h), so we split them for 2x TLP.
// Partial results land in acc_buf[item][hop][64]; stage2 sums both hops.

__global__ __launch_bounds__(256) void ripple_stage1(
    const float* __restrict__ entity_emb,
    const float* __restrict__ relation_emb,
    const float* __restrict__ W_w,
    const float* __restrict__ W_b,
    const int*   __restrict__ item_ids,
    const int*   __restrict__ heads,
    const int*   __restrict__ relations,
    const int*   __restrict__ tails,
    float*       __restrict__ acc_out)   // [N_ITEM][HOPS][DIM]
{
    const int wave = (blockIdx.x * blockDim.x + threadIdx.x) >> 6;  // = h*N_ITEM + i
    const int lane = threadIdx.x & 63;
    if (wave >= HOPS * N_ITEM) return;
    const int h = wave < N_ITEM ? 0 : 1;
    const int i = wave - h * N_ITEM;
    const int g = lane >> 4;
    const int p = lane & 15;

    const f4* __restrict__ E4 = (const f4*)entity_emb;
    const f4* __restrict__ R4 = (const f4*)relation_emb;
    const f4* __restrict__ W4 = (const f4*)W_w;

    const f4 wh = W4[p];
    const f4 wr = W4[16 + p];
    const f4 wt = W4[32 + p];
    const float bias = W_b[0];

    // heads/relations/tails are [H][N_ITEM][N_MEM] flat => base = wave*N_MEM.
    const int base = wave * N_MEM + g;   // this lane's m = 4k+g

    // ---- Phase 0: all 24 indices into registers ----
    int hi[8], ri[8], ti[8];
#pragma unroll
    for (int k = 0; k < 8; ++k) {
        hi[k] = heads[base + 4 * k];
        ri[k] = relations[base + 4 * k];
        ti[k] = tails[base + 4 * k];
    }

    // ---- Phase A: all 24 f4 gathers in flight before any consumption ----
    f4 he[8], re[8], te[8];
#pragma unroll
    for (int k = 0; k < 8; ++k) he[k] = E4[(size_t)hi[k] * 16 + p];
#pragma unroll
    for (int k = 0; k < 8; ++k) re[k] = R4[(size_t)ri[k] * 16 + p];
#pragma unroll
    for (int k = 0; k < 8; ++k) te[k] = E4[(size_t)ti[k] * 16 + p];

    f4 acc = {0.f, 0.f, 0.f, 0.f};
    if (h == 0) {            // wave-uniform branch; exec-masked gather for g==0
        if (g == 0) acc = E4[(size_t)item_ids[i] * 16 + p];
    }

    float part[8];
#pragma unroll
    for (int k = 0; k < 8; ++k) {
        part[k] = he[k].x * wh.x + he[k].y * wh.y + he[k].z * wh.z + he[k].w * wh.w
                + re[k].x * wr.x + re[k].y * wr.y + re[k].z * wr.z + re[k].w * wr.w
                + te[k].x * wt.x + te[k].y * wt.y + te[k].z * wt.z + te[k].w * wt.w;
    }

    // ---- Phase B: 16-lane reduces (4 memories in parallel), sigmoid+exp ----
    float e[8];
    float se = 0.f;
#pragma unroll
    for (int k = 0; k < 8; ++k) {
        float v = part[k];
        v += __shfl_xor(v, 1, 64);
        v += __shfl_xor(v, 2, 64);
        v += __shfl_xor(v, 4, 64);
        v += __shfl_xor(v, 8, 64);
        const float logit = v + bias;
        const float sig   = 1.f / (1.f + __expf(-logit));
        const float ex    = __expf(sig);
        e[k] = ex;
        se += ex;
    }
    se += __shfl_xor(se, 16, 64);
    se += __shfl_xor(se, 32, 64);
    const float inv = 1.f / se;

    // ---- Phase C: weighted tail sum from registers ----
#pragma unroll
    for (int k = 0; k < 8; ++k) {
        const float w = e[k] * inv;
        acc.x += w * te[k].x;
        acc.y += w * te[k].y;
        acc.z += w * te[k].z;
        acc.w += w * te[k].w;
    }

    acc.x += __shfl_xor(acc.x, 16, 64);
    acc.x += __shfl_xor(acc.x, 32, 64);
    acc.y += __shfl_xor(acc.y, 16, 64);
    acc.y += __shfl_xor(acc.y, 32, 64);
    acc.z += __shfl_xor(acc.z, 16, 64);
    acc.z += __shfl_xor(acc.z, 32, 64);
    acc.w += __shfl_xor(acc.w, 16, 64);
    acc.w += __shfl_xor(acc.w, 32, 64);
    if (g == 0) ((f4*)acc_out)[((size_t)i * 2 + h) * 16 + p] = acc;
}

__global__ __launch_bounds__(256) void ripple_stage2(
    const float* __restrict__ entity_emb,
    const int*   __restrict__ records_idx,
    const int*   __restrict__ items,
    const float* __restrict__ acc_buf,   // [N_ITEM][HOPS][DIM]
    float*       __restrict__ out)
{
    const int wave = (blockIdx.x * blockDim.x + threadIdx.x) >> 6;
    const int lane = threadIdx.x & 63;
    if (wave >= BATCH) return;
    const int b = wave;
    const int g = lane >> 4;
    const int p = lane & 15;

    const f4* __restrict__ A4 = (const f4*)acc_buf;
    const f4* __restrict__ E4 = (const f4*)entity_emb;

    const int rb = b * HIST;
    int idx[13];
    float wgt[13];
#pragma unroll
    for (int k = 0; k < 13; ++k) {
        const int j  = 4 * k + g;
        const int jc = j < HIST ? j : (HIST - 1);
        wgt[k] = j < HIST ? 1.f : 0.f;
        idx[k] = records_idx[rb + jc];
    }

    f4 user = {0.f, 0.f, 0.f, 0.f};
#pragma unroll
    for (int k = 0; k < 13; ++k) {
        const size_t r = (size_t)idx[k] * 32 + p;   // row-pair: hop0 @ +0, hop1 @ +16
        const f4 r0 = A4[r];
        const f4 r1 = A4[r + 16];
        user.x += wgt[k] * (r0.x + r1.x);
        user.y += wgt[k] * (r0.y + r1.y);
        user.z += wgt[k] * (r0.z + r1.z);
        user.w += wgt[k] * (r0.w + r1.w);
    }
    user.x += __shfl_xor(user.x, 16, 64);
    user.x += __shfl_xor(user.x, 32, 64);
    user.y += __shfl_xor(user.y, 16, 64);
    user.y += __shfl_xor(user.y, 32, 64);
    user.z += __shfl_xor(user.z, 16, 64);
    user.z += __shfl_xor(user.z, 32, 64);
    user.w += __shfl_xor(user.w, 16, 64);
    user.w += __shfl_xor(user.w, 32, 64);

    const f4 pair = E4[(size_t)items[b] * 16 + p];
    float dot = user.x * pair.x + user.y * pair.y + user.z * pair.z + user.w * pair.w;
    dot += __shfl_xor(dot, 1, 64);
    dot += __shfl_xor(dot, 2, 64);
    dot += __shfl_xor(dot, 4, 64);
    dot += __shfl_xor(dot, 8, 64);
    if (lane == 0) out[b] = 1.f / (1.f + __expf(-dot));
}

extern "C" void kernel_launch(void* const* d_in, const int* in_sizes, int n_in,
                              void* d_out, int out_size, void* d_ws, size_t ws_size,
                              hipStream_t stream) {
    const float* entity_emb   = (const float*)d_in[0];
    const float* relation_emb = (const float*)d_in[1];
    const float* W_w          = (const float*)d_in[2];
    const float* W_b          = (const float*)d_in[3];
    const int*   item_ids     = (const int*)d_in[4];
    const int*   heads        = (const int*)d_in[5];
    const int*   relations    = (const int*)d_in[6];
    const int*   tails        = (const int*)d_in[7];
    const int*   records_idx  = (const int*)d_in[8];
    const int*   items        = (const int*)d_in[9];
    float* out = (float*)d_out;

    float* acc_buf = (float*)d_ws;   // N_ITEM * HOPS * DIM floats = 5.12 MB

    const int waves1  = HOPS * N_ITEM;          // 20000 waves, 4 per block
    const int blocks1 = (waves1 + 3) / 4;
    ripple_stage1<<<blocks1, 256, 0, stream>>>(entity_emb, relation_emb, W_w, W_b,
                                               item_ids, heads, relations, tails,
                                               acc_buf);

    const int blocks2 = (BATCH + 3) / 4;
    ripple_stage2<<<blocks2, 256, 0, stream>>>(entity_emb, records_idx, items,
                                               acc_buf, out);
}

// Round 5
// 228.339 us; speedup vs baseline: 1.0071x; 1.0071x over previous
//
#include <hip/hip_runtime.h>
#include <math.h>

#define DIM    64
#define N_MEM  32
#define N_ITEM 10000
#define HOPS   2
#define BATCH  4096
#define HIST   50

typedef float4 f4;

// Layout: lane = g*16 + p. g = memory subgroup (4 rows gathered per instr),
// p = float4 slot within a 64-float row. One wave instr = 4 rows x 256B.
// One wave per (item, hop); hop partials land in accp[item][hop][64].
// ripple_fold then computes folded[item] = entity[item_ids[item]] + hop0 + hop1
// (2.56MB, per-XCD-L2-resident) which stage2 consumes.

__global__ __launch_bounds__(256) void ripple_stage1(
    const float* __restrict__ entity_emb,
    const float* __restrict__ relation_emb,
    const float* __restrict__ W_w,
    const float* __restrict__ W_b,
    const int*   __restrict__ heads,
    const int*   __restrict__ relations,
    const int*   __restrict__ tails,
    float*       __restrict__ accp)      // [N_ITEM][HOPS][DIM]
{
    const int wave = (blockIdx.x * blockDim.x + threadIdx.x) >> 6;  // = h*N_ITEM + i
    const int lane = threadIdx.x & 63;
    if (wave >= HOPS * N_ITEM) return;
    const int h = wave < N_ITEM ? 0 : 1;
    const int i = wave - h * N_ITEM;
    const int g = lane >> 4;
    const int p = lane & 15;

    const f4* __restrict__ E4 = (const f4*)entity_emb;
    const f4* __restrict__ R4 = (const f4*)relation_emb;
    const f4* __restrict__ W4 = (const f4*)W_w;

    const f4 wh = W4[p];
    const f4 wr = W4[16 + p];
    const f4 wt = W4[32 + p];
    const float bias = W_b[0];

    // heads/relations/tails are [H][N_ITEM][N_MEM] flat => base = wave*N_MEM.
    const int base = wave * N_MEM + g;   // this lane's m = 4k+g

    // ---- Phase 0: all 24 indices into registers ----
    int hi[8], ri[8], ti[8];
#pragma unroll
    for (int k = 0; k < 8; ++k) {
        hi[k] = heads[base + 4 * k];
        ri[k] = relations[base + 4 * k];
        ti[k] = tails[base + 4 * k];
    }

    // ---- Phase A: all 24 f4 gathers in flight before any consumption ----
    f4 he[8], re[8], te[8];
#pragma unroll
    for (int k = 0; k < 8; ++k) he[k] = E4[(size_t)hi[k] * 16 + p];
#pragma unroll
    for (int k = 0; k < 8; ++k) re[k] = R4[(size_t)ri[k] * 16 + p];
#pragma unroll
    for (int k = 0; k < 8; ++k) te[k] = E4[(size_t)ti[k] * 16 + p];

    float part[8];
#pragma unroll
    for (int k = 0; k < 8; ++k) {
        part[k] = he[k].x * wh.x + he[k].y * wh.y + he[k].z * wh.z + he[k].w * wh.w
                + re[k].x * wr.x + re[k].y * wr.y + re[k].z * wr.z + re[k].w * wr.w
                + te[k].x * wt.x + te[k].y * wt.y + te[k].z * wt.z + te[k].w * wt.w;
    }

    // ---- Phase B: 16-lane reduces (4 memories in parallel), sigmoid+exp ----
    float e[8];
    float se = 0.f;
#pragma unroll
    for (int k = 0; k < 8; ++k) {
        float v = part[k];
        v += __shfl_xor(v, 1, 64);
        v += __shfl_xor(v, 2, 64);
        v += __shfl_xor(v, 4, 64);
        v += __shfl_xor(v, 8, 64);
        const float logit = v + bias;
        const float sig   = 1.f / (1.f + __expf(-logit));
        const float ex    = __expf(sig);
        e[k] = ex;
        se += ex;
    }
    se += __shfl_xor(se, 16, 64);
    se += __shfl_xor(se, 32, 64);
    const float inv = 1.f / se;

    // ---- Phase C: weighted tail sum from registers ----
    f4 acc = {0.f, 0.f, 0.f, 0.f};
#pragma unroll
    for (int k = 0; k < 8; ++k) {
        const float w = e[k] * inv;
        acc.x += w * te[k].x;
        acc.y += w * te[k].y;
        acc.z += w * te[k].z;
        acc.w += w * te[k].w;
    }

    acc.x += __shfl_xor(acc.x, 16, 64);
    acc.x += __shfl_xor(acc.x, 32, 64);
    acc.y += __shfl_xor(acc.y, 16, 64);
    acc.y += __shfl_xor(acc.y, 32, 64);
    acc.z += __shfl_xor(acc.z, 16, 64);
    acc.z += __shfl_xor(acc.z, 32, 64);
    acc.w += __shfl_xor(acc.w, 16, 64);
    acc.w += __shfl_xor(acc.w, 32, 64);
    if (g == 0) ((f4*)accp)[((size_t)i * 2 + h) * 16 + p] = acc;
}

// folded[i] = entity[item_ids[i]] + accp[i][0] + accp[i][1]; one f4 per thread.
__global__ __launch_bounds__(256) void ripple_fold(
    const float* __restrict__ entity_emb,
    const int*   __restrict__ item_ids,
    const float* __restrict__ accp,      // [N_ITEM][HOPS][DIM]
    float*       __restrict__ folded)    // [N_ITEM][DIM]
{
    const int t = blockIdx.x * blockDim.x + threadIdx.x;
    if (t >= N_ITEM * 16) return;
    const int i = t >> 4;
    const int p = t & 15;
    const f4* __restrict__ E4 = (const f4*)entity_emb;
    const f4* __restrict__ A4 = (const f4*)accp;
    const f4 a  = A4[(size_t)i * 32 + p];
    const f4 b  = A4[(size_t)i * 32 + 16 + p];
    const f4 it = E4[(size_t)item_ids[i] * 16 + p];
    f4 r;
    r.x = it.x + a.x + b.x;
    r.y = it.y + a.y + b.y;
    r.z = it.z + a.z + b.z;
    r.w = it.w + a.w + b.w;
    ((f4*)folded)[(size_t)i * 16 + p] = r;
}

__global__ __launch_bounds__(256) void ripple_stage2(
    const float* __restrict__ entity_emb,
    const int*   __restrict__ records_idx,
    const int*   __restrict__ items,
    const float* __restrict__ folded,    // [N_ITEM][DIM], L2-resident
    float*       __restrict__ out)
{
    const int wave = (blockIdx.x * blockDim.x + threadIdx.x) >> 6;
    const int lane = threadIdx.x & 63;
    if (wave >= BATCH) return;
    const int b = wave;
    const int g = lane >> 4;
    const int p = lane & 15;

    const f4* __restrict__ A4 = (const f4*)folded;
    const f4* __restrict__ E4 = (const f4*)entity_emb;

    const int rb = b * HIST;
    int idx[13];
    float wgt[13];
#pragma unroll
    for (int k = 0; k < 13; ++k) {
        const int j  = 4 * k + g;
        const int jc = j < HIST ? j : (HIST - 1);
        wgt[k] = j < HIST ? 1.f : 0.f;
        idx[k] = records_idx[rb + jc];
    }

    f4 user = {0.f, 0.f, 0.f, 0.f};
#pragma unroll
    for (int k = 0; k < 13; ++k) {
        const f4 r = A4[(size_t)idx[k] * 16 + p];
        user.x += wgt[k] * r.x;
        user.y += wgt[k] * r.y;
        user.z += wgt[k] * r.z;
        user.w += wgt[k] * r.w;
    }
    user.x += __shfl_xor(user.x, 16, 64);
    user.x += __shfl_xor(user.x, 32, 64);
    user.y += __shfl_xor(user.y, 16, 64);
    user.y += __shfl_xor(user.y, 32, 64);
    user.z += __shfl_xor(user.z, 16, 64);
    user.z += __shfl_xor(user.z, 32, 64);
    user.w += __shfl_xor(user.w, 16, 64);
    user.w += __shfl_xor(user.w, 32, 64);

    const f4 pair = E4[(size_t)items[b] * 16 + p];
    float dot = user.x * pair.x + user.y * pair.y + user.z * pair.z + user.w * pair.w;
    dot += __shfl_xor(dot, 1, 64);
    dot += __shfl_xor(dot, 2, 64);
    dot += __shfl_xor(dot, 4, 64);
    dot += __shfl_xor(dot, 8, 64);
    if (lane == 0) out[b] = 1.f / (1.f + __expf(-dot));
}

extern "C" void kernel_launch(void* const* d_in, const int* in_sizes, int n_in,
                              void* d_out, int out_size, void* d_ws, size_t ws_size,
                              hipStream_t stream) {
    const float* entity_emb   = (const float*)d_in[0];
    const float* relation_emb = (const float*)d_in[1];
    const float* W_w          = (const float*)d_in[2];
    const float* W_b          = (const float*)d_in[3];
    const int*   item_ids     = (const int*)d_in[4];
    const int*   heads        = (const int*)d_in[5];
    const int*   relations    = (const int*)d_in[6];
    const int*   tails        = (const int*)d_in[7];
    const int*   records_idx  = (const int*)d_in[8];
    const int*   items        = (const int*)d_in[9];
    float* out = (float*)d_out;

    float* accp   = (float*)d_ws;                         // 5.12 MB
    float* folded = accp + (size_t)N_ITEM * HOPS * DIM;   // 2.56 MB

    const int waves1  = HOPS * N_ITEM;          // 20000 waves, 4 per block
    const int blocks1 = (waves1 + 3) / 4;
    ripple_stage1<<<blocks1, 256, 0, stream>>>(entity_emb, relation_emb, W_w, W_b,
                                               heads, relations, tails, accp);

    const int blocksF = (N_ITEM * 16 + 255) / 256;
    ripple_fold<<<blocksF, 256, 0, stream>>>(entity_emb, item_ids, accp, folded);

    const int blocks2 = (BATCH + 3) / 4;
    ripple_stage2<<<blocks2, 256, 0, stream>>>(entity_emb, records_idx, items,
                                               folded, out);
}